// Round 1
// baseline (363.528 us; speedup 1.0000x reference)
//
#include <hip/hip_runtime.h>

typedef __bf16 bf16;
typedef __bf16 bf16x8 __attribute__((ext_vector_type(8)));
typedef float f32x4 __attribute__((ext_vector_type(4)));
typedef unsigned int uint;
typedef unsigned short ushort;

typedef const __attribute__((address_space(1))) void* gas_ptr;
typedef __attribute__((address_space(3))) void* las_ptr;

__device__ __forceinline__ void load16_lds(const void* g, void* l) {
  __builtin_amdgcn_global_load_lds((gas_ptr)g, (las_ptr)l, 16, 0, 0);
}

// ---------------------------------------------------------------------------
// x fp32 -> bf16 cast (8 elems/thread)
// ---------------------------------------------------------------------------
__global__ __launch_bounds__(256) void cast_f32_bf16(
    const float* __restrict__ in, bf16* __restrict__ out) {
  size_t i = (size_t)blockIdx.x * 256 + threadIdx.x;
  const float4* p = reinterpret_cast<const float4*>(in) + i * 2;
  float4 a = p[0], b = p[1];
  bf16x8 v;
  v[0] = (bf16)a.x; v[1] = (bf16)a.y; v[2] = (bf16)a.z; v[3] = (bf16)a.w;
  v[4] = (bf16)b.x; v[5] = (bf16)b.y; v[6] = (bf16)b.z; v[7] = (bf16)b.w;
  reinterpret_cast<bf16x8*>(out)[i] = v;
}

// ---------------------------------------------------------------------------
// Weight transpose + cast: in [K][N] fp32 -> out [N][K] bf16, 64x64 tiles
// ---------------------------------------------------------------------------
__global__ __launch_bounds__(256) void transpose_f32_bf16(
    const float* __restrict__ in, bf16* __restrict__ out, int K, int N) {
  __shared__ __attribute__((aligned(16))) bf16 tile[64 * 72];
  const int k0 = blockIdx.y * 64, n0 = blockIdx.x * 64;
  const int tid = threadIdx.x;
  for (int c = tid; c < 1024; c += 256) {
    int ki = c >> 4, j4 = c & 15;
    float4 f = *reinterpret_cast<const float4*>(in + (size_t)(k0 + ki) * N + n0 + j4 * 4);
    bf16* t = &tile[ki * 72 + j4 * 4];
    t[0] = (bf16)f.x; t[1] = (bf16)f.y; t[2] = (bf16)f.z; t[3] = (bf16)f.w;
  }
  __syncthreads();
  for (int c = tid; c < 512; c += 256) {
    int ni = c >> 3, k8 = c & 7;
    bf16x8 v;
    for (int j = 0; j < 8; j++) v[j] = tile[(k8 * 8 + j) * 72 + ni];
    *reinterpret_cast<bf16x8*>(out + (size_t)(n0 + ni) * K + k0 + k8 * 8) = v;
  }
}

// ---------------------------------------------------------------------------
// GEMM: C[M,N] = A[M,K] * Bt[N,K]^T  (bf16 in, f32 accum, CT out)
// 128x128 tile, BK=64. Staging via global_load_lds width=16.
// LDS chunk layout: 16B chunk p holds logical (row=p>>3, kc=(p&7)^(row&7)).
// Fragment read for (row,kc): chunk row*8 + (kc^(row&7)) -> bank-even b128s.
// ---------------------------------------------------------------------------
template <typename CT>
__global__ __launch_bounds__(256, 2) void gemm_lds(
    const bf16* __restrict__ A, const bf16* __restrict__ Bt,
    CT* __restrict__ C, int M, int N, int K) {
  __shared__ __attribute__((aligned(16))) bf16 As[128 * 64];
  __shared__ __attribute__((aligned(16))) bf16 Bs[128 * 64];
  const int tid = threadIdx.x;
  const int wave = tid >> 6;
  const int lane = tid & 63;
  const int l15 = lane & 15;
  const int quad = lane >> 4;
  const int m0 = blockIdx.y * 128;
  const int n0 = blockIdx.x * 128;
  const int wm = (wave >> 1) * 64;
  const int wn = (wave & 1) * 64;

  f32x4 acc[4][4] = {};

  for (int kt = 0; kt < K; kt += 64) {
    __syncthreads();
    for (int it = 0; it < 4; ++it) {
      int p = it * 256 + wave * 64 + lane;
      int row = p >> 3, kc = (p & 7) ^ (row & 7);
      load16_lds(A + (size_t)(m0 + row) * K + kt + kc * 8, &As[p * 8]);
      load16_lds(Bt + (size_t)(n0 + row) * K + kt + kc * 8, &Bs[p * 8]);
    }
    __syncthreads();
    for (int kk = 0; kk < 64; kk += 32) {
      const int kc = (kk >> 3) + quad;
      bf16x8 af[4], bfr[4];
      for (int i = 0; i < 4; i++) {
        int row = wm + i * 16 + l15;
        af[i] = *reinterpret_cast<const bf16x8*>(&As[(row * 8 + (kc ^ (row & 7))) * 8]);
      }
      for (int j = 0; j < 4; j++) {
        int row = wn + j * 16 + l15;
        bfr[j] = *reinterpret_cast<const bf16x8*>(&Bs[(row * 8 + (kc ^ (row & 7))) * 8]);
      }
      for (int i = 0; i < 4; i++)
        for (int j = 0; j < 4; j++)
          acc[i][j] = __builtin_amdgcn_mfma_f32_16x16x32_bf16(af[i], bfr[j], acc[i][j], 0, 0, 0);
    }
  }

  for (int i = 0; i < 4; i++)
    for (int j = 0; j < 4; j++)
      for (int r = 0; r < 4; r++) {
        int row = m0 + wm + i * 16 + quad * 4 + r;
        int col = n0 + wn + j * 16 + l15;
        C[(size_t)row * N + col] = (CT)acc[i][j][r];
      }
}

// ---------------------------------------------------------------------------
// Flash attention. qkv: [B*T, 3072] bf16, col = s*1024 + h*64 + d.
// Grid (B*H=64, T/64=32); 4 waves x 16 q-rows.
// Q pre-scaled by log2(e); row-sum via ones-column MFMA.
// Vs: [d][key] as dwords (key pairs), XOR-swizzled; Ps: fp32, stride 68.
// T14 async-STAGE: K/V tile t+1 global->reg loads issued before compute of
// tile t; reg->LDS writes land after the next barrier. setprio around MFMA.
// ---------------------------------------------------------------------------
__device__ __forceinline__ int vs_dw(int d, int kdw) {
  return d * 32 + (kdw ^ ((((d >> 3) ^ d) & 7) * 4));
}

__global__ __launch_bounds__(256, 2) void attn_kernel(
    const bf16* __restrict__ qkv, bf16* __restrict__ out) {
  __shared__ __attribute__((aligned(16))) bf16 Ks[64 * 72];   // [key][d], pad 72
  __shared__ __attribute__((aligned(16))) uint Vs[64 * 32];   // swizzled [d][keypair]
  __shared__ __attribute__((aligned(16))) float Ps[4][16 * 68];

  const int tid = threadIdx.x;
  const int wave = tid >> 6;
  const int lane = tid & 63;
  const int l15 = lane & 15;
  const int quad = lane >> 4;
  const int b = blockIdx.x >> 4;
  const int h = blockIdx.x & 15;
  const int qt0 = blockIdx.y * 64;
  const bf16* base = qkv + (size_t)b * 2048 * 3072 + h * 64;
  float* Pw = &Ps[wave][0];
  const float L2E = 1.44269504f;

  // Q fragments, pre-scaled by log2(e)
  bf16x8 aq0, aq1;
  {
    const bf16* qrow = base + (size_t)(qt0 + wave * 16 + l15) * 3072;
    aq0 = *reinterpret_cast<const bf16x8*>(qrow + quad * 8);
    aq1 = *reinterpret_cast<const bf16x8*>(qrow + 32 + quad * 8);
    for (int j = 0; j < 8; j++) {
      aq0[j] = (bf16)((float)aq0[j] * L2E);
      aq1[j] = (bf16)((float)aq1[j] * L2E);
    }
  }

  // ones-column B fragment: B[k][0] = 1 -> lanes with l15==0 hold 1s
  bf16x8 bones = {};
  if (l15 == 0)
    for (int j = 0; j < 8; j++) bones[j] = (bf16)1.0f;

  float m_r[4];
  f32x4 o[4] = {};
  f32x4 l_acc = {};
  for (int r = 0; r < 4; r++) m_r[r] = -1e30f;

  const int kp = tid >> 3;   // key pair 0..31
  const int oct = tid & 7;   // d octet 0..7
  const int kkey = tid >> 3; // K-stage: key row (c>>3 for c=tid)
  const int kk8 = tid & 7;   // K-stage: d octet

  // ---- prologue: prefetch KV tile 0 into registers ----
  bf16x8 kpre0, kpre1, vpre0, vpre1;
  {
    const bf16* kb = base + 1024 + (size_t)kkey * 3072 + kk8 * 8;
    kpre0 = *reinterpret_cast<const bf16x8*>(kb);
    kpre1 = *reinterpret_cast<const bf16x8*>(kb + (size_t)32 * 3072);
    const bf16* v0p = base + (size_t)(2 * kp) * 3072 + 2048 + oct * 8;
    vpre0 = *reinterpret_cast<const bf16x8*>(v0p);
    vpre1 = *reinterpret_cast<const bf16x8*>(v0p + 3072);
  }

  for (int kt = 0; kt < 2048; kt += 64) {
    __syncthreads();
    // ---- write prefetched tile into LDS ----
    *reinterpret_cast<bf16x8*>(&Ks[kkey * 72 + kk8 * 8]) = kpre0;
    *reinterpret_cast<bf16x8*>(&Ks[(kkey + 32) * 72 + kk8 * 8]) = kpre1;
    {
      const ushort* u0 = reinterpret_cast<const ushort*>(&vpre0);
      const ushort* u1 = reinterpret_cast<const ushort*>(&vpre1);
      for (int i = 0; i < 8; i++)
        Vs[vs_dw(oct * 8 + i, kp)] = (uint)u0[i] | ((uint)u1[i] << 16);
    }
    __syncthreads();

    // ---- issue next-tile global loads; latency hides under compute ----
    if (kt + 64 < 2048) {
      const bf16* nb = base + (size_t)(kt + 64) * 3072;
      const bf16* kb = nb + 1024 + (size_t)kkey * 3072 + kk8 * 8;
      kpre0 = *reinterpret_cast<const bf16x8*>(kb);
      kpre1 = *reinterpret_cast<const bf16x8*>(kb + (size_t)32 * 3072);
      const bf16* v0p = nb + (size_t)(2 * kp) * 3072 + 2048 + oct * 8;
      vpre0 = *reinterpret_cast<const bf16x8*>(v0p);
      vpre1 = *reinterpret_cast<const bf16x8*>(v0p + 3072);
    }

    // S' = (Q*log2e) K^T
    f32x4 s[4];
    __builtin_amdgcn_s_setprio(1);
    for (int n = 0; n < 4; n++) {
      bf16x8 bk0 = *reinterpret_cast<const bf16x8*>(&Ks[(n * 16 + l15) * 72 + quad * 8]);
      bf16x8 bk1 = *reinterpret_cast<const bf16x8*>(&Ks[(n * 16 + l15) * 72 + 32 + quad * 8]);
      f32x4 z = {};
      z = __builtin_amdgcn_mfma_f32_16x16x32_bf16(aq0, bk0, z, 0, 0, 0);
      z = __builtin_amdgcn_mfma_f32_16x16x32_bf16(aq1, bk1, z, 0, 0, 0);
      s[n] = z;
    }
    __builtin_amdgcn_s_setprio(0);

    // online softmax (log2 domain); P -> fp32 LDS (conflict-free stores)
    for (int r = 0; r < 4; r++) {
      float v0 = fmaxf(fmaxf(s[0][r], s[1][r]), fmaxf(s[2][r], s[3][r]));
      for (int m = 1; m <= 8; m <<= 1) v0 = fmaxf(v0, __shfl_xor(v0, m, 64));
      float mn = fmaxf(m_r[r], v0);
      float alpha = __builtin_amdgcn_exp2f(m_r[r] - mn);
      m_r[r] = mn;
      l_acc[r] *= alpha;
      for (int n = 0; n < 4; n++) {
        float p = __builtin_amdgcn_exp2f(s[n][r] - mn);
        o[n][r] *= alpha;
        Pw[(quad * 4 + r) * 68 + n * 16 + l15] = p;
      }
    }

    // P fragments (fp32 LDS -> bf16), wave-synchronous
    bf16x8 ap0, ap1;
    {
      float4 f0 = *reinterpret_cast<const float4*>(&Pw[l15 * 68 + quad * 8]);
      float4 f1 = *reinterpret_cast<const float4*>(&Pw[l15 * 68 + quad * 8 + 4]);
      float4 g0 = *reinterpret_cast<const float4*>(&Pw[l15 * 68 + 32 + quad * 8]);
      float4 g1 = *reinterpret_cast<const float4*>(&Pw[l15 * 68 + 32 + quad * 8 + 4]);
      ap0[0] = (bf16)f0.x; ap0[1] = (bf16)f0.y; ap0[2] = (bf16)f0.z; ap0[3] = (bf16)f0.w;
      ap0[4] = (bf16)f1.x; ap0[5] = (bf16)f1.y; ap0[6] = (bf16)f1.z; ap0[7] = (bf16)f1.w;
      ap1[0] = (bf16)g0.x; ap1[1] = (bf16)g0.y; ap1[2] = (bf16)g0.z; ap1[3] = (bf16)g0.w;
      ap1[4] = (bf16)g1.x; ap1[5] = (bf16)g1.y; ap1[6] = (bf16)g1.z; ap1[7] = (bf16)g1.w;
    }

    __builtin_amdgcn_s_setprio(1);
    // row-sum via ones-column
    l_acc = __builtin_amdgcn_mfma_f32_16x16x32_bf16(ap0, bones, l_acc, 0, 0, 0);
    l_acc = __builtin_amdgcn_mfma_f32_16x16x32_bf16(ap1, bones, l_acc, 0, 0, 0);

    // O += P V  (V fragments from swizzled Vs)
    for (int n = 0; n < 4; n++) {
      int d = n * 16 + l15;
      uint4 u0 = *reinterpret_cast<const uint4*>(&Vs[vs_dw(d, quad * 4)]);
      uint4 u1 = *reinterpret_cast<const uint4*>(&Vs[vs_dw(d, 16 + quad * 4)]);
      bf16x8 bv0 = *reinterpret_cast<const bf16x8*>(&u0);
      bf16x8 bv1 = *reinterpret_cast<const bf16x8*>(&u1);
      o[n] = __builtin_amdgcn_mfma_f32_16x16x32_bf16(ap0, bv0, o[n], 0, 0, 0);
      o[n] = __builtin_amdgcn_mfma_f32_16x16x32_bf16(ap1, bv1, o[n], 0, 0, 0);
    }
    __builtin_amdgcn_s_setprio(0);
  }

  for (int r = 0; r < 4; r++) {
    float lv = __shfl(l_acc[r], quad * 16, 64);
    float inv = 1.0f / lv;
    int q = qt0 + wave * 16 + quad * 4 + r;
    bf16* orow = out + (size_t)(b * 2048 + q) * 1024 + h * 64;
    for (int n = 0; n < 4; n++) orow[n * 16 + l15] = (bf16)(o[n][r] * inv);
  }
}

// ---------------------------------------------------------------------------
// Launch
// ---------------------------------------------------------------------------
extern "C" void kernel_launch(void* const* d_in, const int* in_sizes, int n_in,
                              void* d_out, int out_size, void* d_ws, size_t ws_size,
                              hipStream_t stream) {
  const float* x = (const float*)d_in[0];       // [8192, 1024] fp32
  const float* w_qkv = (const float*)d_in[1];   // [1024, 3072] fp32
  const float* w_proj = (const float*)d_in[2];  // [1024, 1024] fp32
  float* out = (float*)d_out;                   // [8192, 1024] fp32

  bf16* ws = (bf16*)d_ws;
  bf16* x_bf = ws;                                   // [8192,1024]
  bf16* wqkvT = x_bf + (size_t)8192 * 1024;          // [3072,1024]
  bf16* wprojT = wqkvT + 3072 * 1024;                // [1024,1024]
  bf16* qkv = wprojT + 1024 * 1024;                  // [8192,3072]
  bf16* attn_out = qkv + (size_t)8192 * 3072;        // [8192,1024]

  cast_f32_bf16<<<4096, 256, 0, stream>>>(x, x_bf);
  transpose_f32_bf16<<<dim3(48, 16), 256, 0, stream>>>(w_qkv, wqkvT, 1024, 3072);
  transpose_f32_bf16<<<dim3(16, 16), 256, 0, stream>>>(w_proj, wprojT, 1024, 1024);
  gemm_lds<bf16><<<dim3(24, 64), 256, 0, stream>>>(x_bf, wqkvT, qkv, 8192, 3072, 1024);
  attn_kernel<<<dim3(64, 32), 256, 0, stream>>>(qkv, attn_out);
  gemm_lds<float><<<dim3(8, 64), 256, 0, stream>>>(attn_out, wprojT, out, 8192, 1024, 1024);
}

// Round 2
// 281.830 us; speedup vs baseline: 1.2899x; 1.2899x over previous
//
#include <hip/hip_runtime.h>

typedef __bf16 bf16;
typedef __bf16 bf16x8 __attribute__((ext_vector_type(8)));
typedef float f32x4 __attribute__((ext_vector_type(4)));
typedef unsigned int uint;
typedef unsigned short ushort;

typedef const __attribute__((address_space(1))) void* gas_ptr;
typedef __attribute__((address_space(3))) void* las_ptr;

__device__ __forceinline__ void load16_lds(const void* g, void* l) {
  __builtin_amdgcn_global_load_lds((gas_ptr)g, (las_ptr)l, 16, 0, 0);
}

// ---------------------------------------------------------------------------
// x fp32 -> bf16 cast (8 elems/thread)
// ---------------------------------------------------------------------------
__global__ __launch_bounds__(256) void cast_f32_bf16(
    const float* __restrict__ in, bf16* __restrict__ out) {
  size_t i = (size_t)blockIdx.x * 256 + threadIdx.x;
  const float4* p = reinterpret_cast<const float4*>(in) + i * 2;
  float4 a = p[0], b = p[1];
  bf16x8 v;
  v[0] = (bf16)a.x; v[1] = (bf16)a.y; v[2] = (bf16)a.z; v[3] = (bf16)a.w;
  v[4] = (bf16)b.x; v[5] = (bf16)b.y; v[6] = (bf16)b.z; v[7] = (bf16)b.w;
  reinterpret_cast<bf16x8*>(out)[i] = v;
}

// ---------------------------------------------------------------------------
// Weight transpose + cast: in [K][N] fp32 -> out [N][K] bf16, 64x64 tiles
// ---------------------------------------------------------------------------
__global__ __launch_bounds__(256) void transpose_f32_bf16(
    const float* __restrict__ in, bf16* __restrict__ out, int K, int N) {
  __shared__ __attribute__((aligned(16))) bf16 tile[64 * 72];
  const int k0 = blockIdx.y * 64, n0 = blockIdx.x * 64;
  const int tid = threadIdx.x;
  for (int c = tid; c < 1024; c += 256) {
    int ki = c >> 4, j4 = c & 15;
    float4 f = *reinterpret_cast<const float4*>(in + (size_t)(k0 + ki) * N + n0 + j4 * 4);
    bf16* t = &tile[ki * 72 + j4 * 4];
    t[0] = (bf16)f.x; t[1] = (bf16)f.y; t[2] = (bf16)f.z; t[3] = (bf16)f.w;
  }
  __syncthreads();
  for (int c = tid; c < 512; c += 256) {
    int ni = c >> 3, k8 = c & 7;
    bf16x8 v;
    for (int j = 0; j < 8; j++) v[j] = tile[(k8 * 8 + j) * 72 + ni];
    *reinterpret_cast<bf16x8*>(out + (size_t)(n0 + ni) * K + k0 + k8 * 8) = v;
  }
}

// ---------------------------------------------------------------------------
// GEMM: C[M,N] = A[M,K] * Bt[N,K]^T  (bf16 in, f32 accum, CT out)
// 128x128 tile, BK=64. Staging via global_load_lds width=16.
// LDS chunk layout: 16B chunk p holds logical (row=p>>3, kc=(p&7)^(row&7)).
// Fragment read for (row,kc): chunk row*8 + (kc^(row&7)) -> bank-even b128s.
// ---------------------------------------------------------------------------
template <typename CT>
__global__ __launch_bounds__(256, 2) void gemm_lds(
    const bf16* __restrict__ A, const bf16* __restrict__ Bt,
    CT* __restrict__ C, int M, int N, int K) {
  __shared__ __attribute__((aligned(16))) bf16 As[128 * 64];
  __shared__ __attribute__((aligned(16))) bf16 Bs[128 * 64];
  const int tid = threadIdx.x;
  const int wave = tid >> 6;
  const int lane = tid & 63;
  const int l15 = lane & 15;
  const int quad = lane >> 4;
  const int m0 = blockIdx.y * 128;
  const int n0 = blockIdx.x * 128;
  const int wm = (wave >> 1) * 64;
  const int wn = (wave & 1) * 64;

  f32x4 acc[4][4] = {};

  for (int kt = 0; kt < K; kt += 64) {
    __syncthreads();
    for (int it = 0; it < 4; ++it) {
      int p = it * 256 + wave * 64 + lane;
      int row = p >> 3, kc = (p & 7) ^ (row & 7);
      load16_lds(A + (size_t)(m0 + row) * K + kt + kc * 8, &As[p * 8]);
      load16_lds(Bt + (size_t)(n0 + row) * K + kt + kc * 8, &Bs[p * 8]);
    }
    __syncthreads();
    for (int kk = 0; kk < 64; kk += 32) {
      const int kc = (kk >> 3) + quad;
      bf16x8 af[4], bfr[4];
      for (int i = 0; i < 4; i++) {
        int row = wm + i * 16 + l15;
        af[i] = *reinterpret_cast<const bf16x8*>(&As[(row * 8 + (kc ^ (row & 7))) * 8]);
      }
      for (int j = 0; j < 4; j++) {
        int row = wn + j * 16 + l15;
        bfr[j] = *reinterpret_cast<const bf16x8*>(&Bs[(row * 8 + (kc ^ (row & 7))) * 8]);
      }
      for (int i = 0; i < 4; i++)
        for (int j = 0; j < 4; j++)
          acc[i][j] = __builtin_amdgcn_mfma_f32_16x16x32_bf16(af[i], bfr[j], acc[i][j], 0, 0, 0);
    }
  }

  for (int i = 0; i < 4; i++)
    for (int j = 0; j < 4; j++)
      for (int r = 0; r < 4; r++) {
        int row = m0 + wm + i * 16 + quad * 4 + r;
        int col = n0 + wn + j * 16 + l15;
        C[(size_t)row * N + col] = (CT)acc[i][j][r];
      }
}

// ---------------------------------------------------------------------------
// Flash attention, swapped-QK^T form. qkv: [B*T, 3072] bf16.
// Grid (B*H=64, T/64=32); 4 waves x 16 q-rows.
//
// S^T = mfma(A=K_frag, B=Q_frag): lane holds 16 scores for query l15.
// K rows are placed permuted in LDS: key kk -> row rho(kk) (bit2 <-> bits3-4)
// so that the S^T C-registers are exactly PV's A-fragment order:
//   ap0[j] = P[l15][quad*8 + j], ap1[j] = P[l15][32 + quad*8 + j].
// No P LDS round-trip, no cross-lane P exchange.
// Softmax: in-lane max over 16 + shfl_xor(16,32); defer-max threshold 8.
// alpha/l/o rescale uses 4 shfl pulls into C-layout rows (query = quad*4+r).
// Ks uses GEMM-style XOR-chunk layout (conflict-free b128 reads).
// Vs: [d][keypair] dwords, XOR-swizzled (unchanged).
// ---------------------------------------------------------------------------
__device__ __forceinline__ int vs_dw(int d, int kdw) {
  return d * 32 + (kdw ^ ((((d >> 3) ^ d) & 7) * 4));
}

__global__ __launch_bounds__(256, 4) void attn_kernel(
    const bf16* __restrict__ qkv, bf16* __restrict__ out) {
  __shared__ __attribute__((aligned(16))) bf16 Ks[64 * 64];   // XOR-chunk, rho-rows
  __shared__ __attribute__((aligned(16))) uint Vs[64 * 32];   // swizzled [d][keypair]

  const int tid = threadIdx.x;
  const int wave = tid >> 6;
  const int lane = tid & 63;
  const int l15 = lane & 15;
  const int quad = lane >> 4;
  const int b = blockIdx.x >> 4;
  const int h = blockIdx.x & 15;
  const int qt0 = blockIdx.y * 64;
  const bf16* base = qkv + (size_t)b * 2048 * 3072 + h * 64;
  const float L2E = 1.44269504f;

  // Q fragments (B-operand), pre-scaled by log2(e)
  bf16x8 aq0, aq1;
  {
    const bf16* qrow = base + (size_t)(qt0 + wave * 16 + l15) * 3072;
    aq0 = *reinterpret_cast<const bf16x8*>(qrow + quad * 8);
    aq1 = *reinterpret_cast<const bf16x8*>(qrow + 32 + quad * 8);
    for (int j = 0; j < 8; j++) {
      aq0[j] = (bf16)((float)aq0[j] * L2E);
      aq1[j] = (bf16)((float)aq1[j] * L2E);
    }
  }

  // ones-column B fragment: B[k][0] = 1 -> lanes with l15==0 hold 1s
  bf16x8 bones = {};
  if (l15 == 0)
    for (int j = 0; j < 8; j++) bones[j] = (bf16)1.0f;

  float m_q = -1e30f;     // running max for query l15 (replicated across quads)
  f32x4 o[4] = {};
  f32x4 l_acc = {};

  const int kp = tid >> 3;   // key pair 0..31 (V staging)
  const int oct = tid & 7;   // d octet 0..7 (V staging)
  const int kkey = tid >> 3; // K staging: key row 0..31 (and +32)
  const int kk8 = tid & 7;   // K staging: d chunk
  // permuted LDS row for key kkey: rho = a<<4 | q<<2 | r  (kkey = q<<3|a<<2|r)
  const int prow = ((kkey & 4) << 2) | ((kkey & 24) >> 1) | (kkey & 3);
  const int kxor = kk8 ^ (prow & 7);               // same for prow and prow+32
  const int kdst0 = (prow * 8 + kxor) * 8;
  const int kdst1 = kdst0 + 32 * 64;

  // ---- prologue: prefetch KV tile 0 into registers ----
  bf16x8 kpre0, kpre1, vpre0, vpre1;
  {
    const bf16* kb = base + 1024 + (size_t)kkey * 3072 + kk8 * 8;
    kpre0 = *reinterpret_cast<const bf16x8*>(kb);
    kpre1 = *reinterpret_cast<const bf16x8*>(kb + (size_t)32 * 3072);
    const bf16* v0p = base + (size_t)(2 * kp) * 3072 + 2048 + oct * 8;
    vpre0 = *reinterpret_cast<const bf16x8*>(v0p);
    vpre1 = *reinterpret_cast<const bf16x8*>(v0p + 3072);
  }

  for (int kt = 0; kt < 2048; kt += 64) {
    __syncthreads();
    // ---- write prefetched tile into LDS ----
    *reinterpret_cast<bf16x8*>(&Ks[kdst0]) = kpre0;
    *reinterpret_cast<bf16x8*>(&Ks[kdst1]) = kpre1;
    {
      const ushort* u0 = reinterpret_cast<const ushort*>(&vpre0);
      const ushort* u1 = reinterpret_cast<const ushort*>(&vpre1);
      for (int i = 0; i < 8; i++)
        Vs[vs_dw(oct * 8 + i, kp)] = (uint)u0[i] | ((uint)u1[i] << 16);
    }
    __syncthreads();

    // ---- issue next-tile global loads; latency hides under compute ----
    if (kt + 64 < 2048) {
      const bf16* nb = base + (size_t)(kt + 64) * 3072;
      const bf16* kb = nb + 1024 + (size_t)kkey * 3072 + kk8 * 8;
      kpre0 = *reinterpret_cast<const bf16x8*>(kb);
      kpre1 = *reinterpret_cast<const bf16x8*>(kb + (size_t)32 * 3072);
      const bf16* v0p = nb + (size_t)(2 * kp) * 3072 + 2048 + oct * 8;
      vpre0 = *reinterpret_cast<const bf16x8*>(v0p);
      vpre1 = *reinterpret_cast<const bf16x8*>(v0p + 3072);
    }

    // ---- S^T = K (Q*log2e)^T : mfma(A=K_frag, B=Q_frag) ----
    f32x4 s[4];
    __builtin_amdgcn_s_setprio(1);
    for (int n = 0; n < 4; n++) {
      int row = n * 16 + l15;
      int xr = row & 7;
      bf16x8 ak0 = *reinterpret_cast<const bf16x8*>(&Ks[(row * 8 + (quad ^ xr)) * 8]);
      bf16x8 ak1 = *reinterpret_cast<const bf16x8*>(&Ks[(row * 8 + ((4 + quad) ^ xr)) * 8]);
      f32x4 z = {};
      z = __builtin_amdgcn_mfma_f32_16x16x32_bf16(ak0, aq0, z, 0, 0, 0);
      z = __builtin_amdgcn_mfma_f32_16x16x32_bf16(ak1, aq1, z, 0, 0, 0);
      s[n] = z;
    }
    __builtin_amdgcn_s_setprio(0);

    // ---- per-query online softmax, fully in-register ----
    float mt = fmaxf(fmaxf(s[0][0], s[0][1]), fmaxf(s[0][2], s[0][3]));
    mt = fmaxf(mt, fmaxf(fmaxf(s[1][0], s[1][1]), fmaxf(s[1][2], s[1][3])));
    mt = fmaxf(mt, fmaxf(fmaxf(s[2][0], s[2][1]), fmaxf(s[2][2], s[2][3])));
    mt = fmaxf(mt, fmaxf(fmaxf(s[3][0], s[3][1]), fmaxf(s[3][2], s[3][3])));
    mt = fmaxf(mt, __shfl_xor(mt, 16, 64));
    mt = fmaxf(mt, __shfl_xor(mt, 32, 64));

    // defer-max: only rescale when the tile max grew by > 8 (log2 domain)
    if (!__all(mt - m_q <= 8.0f)) {
      float mn = fmaxf(m_q, mt);
      float alpha = __builtin_amdgcn_exp2f(m_q - mn);
      m_q = mn;
      // pull alphas into C-layout rows (query = quad*4 + r)
      float a0 = __shfl(alpha, quad * 4 + 0, 64);
      float a1 = __shfl(alpha, quad * 4 + 1, 64);
      float a2 = __shfl(alpha, quad * 4 + 2, 64);
      float a3 = __shfl(alpha, quad * 4 + 3, 64);
      l_acc[0] *= a0; l_acc[1] *= a1; l_acc[2] *= a2; l_acc[3] *= a3;
      for (int n = 0; n < 4; n++) {
        o[n][0] *= a0; o[n][1] *= a1; o[n][2] *= a2; o[n][3] *= a3;
      }
    }

    // P in PV A-fragment order directly (thanks to rho-permuted K rows)
    bf16x8 ap0, ap1;
    for (int r = 0; r < 4; r++) {
      ap0[r]     = (bf16)__builtin_amdgcn_exp2f(s[0][r] - m_q);
      ap0[4 + r] = (bf16)__builtin_amdgcn_exp2f(s[1][r] - m_q);
      ap1[r]     = (bf16)__builtin_amdgcn_exp2f(s[2][r] - m_q);
      ap1[4 + r] = (bf16)__builtin_amdgcn_exp2f(s[3][r] - m_q);
    }

    __builtin_amdgcn_s_setprio(1);
    // row-sum via ones-column (C-layout rows = queries quad*4+r)
    l_acc = __builtin_amdgcn_mfma_f32_16x16x32_bf16(ap0, bones, l_acc, 0, 0, 0);
    l_acc = __builtin_amdgcn_mfma_f32_16x16x32_bf16(ap1, bones, l_acc, 0, 0, 0);

    // O += P V  (V fragments from swizzled Vs)
    for (int n = 0; n < 4; n++) {
      int d = n * 16 + l15;
      uint4 u0 = *reinterpret_cast<const uint4*>(&Vs[vs_dw(d, quad * 4)]);
      uint4 u1 = *reinterpret_cast<const uint4*>(&Vs[vs_dw(d, 16 + quad * 4)]);
      bf16x8 bv0 = *reinterpret_cast<const bf16x8*>(&u0);
      bf16x8 bv1 = *reinterpret_cast<const bf16x8*>(&u1);
      o[n] = __builtin_amdgcn_mfma_f32_16x16x32_bf16(ap0, bv0, o[n], 0, 0, 0);
      o[n] = __builtin_amdgcn_mfma_f32_16x16x32_bf16(ap1, bv1, o[n], 0, 0, 0);
    }
    __builtin_amdgcn_s_setprio(0);
  }

  for (int r = 0; r < 4; r++) {
    float lv = __shfl(l_acc[r], quad * 16, 64);
    float inv = 1.0f / lv;
    int q = qt0 + wave * 16 + quad * 4 + r;
    bf16* orow = out + (size_t)(b * 2048 + q) * 1024 + h * 64;
    for (int n = 0; n < 4; n++) orow[n * 16 + l15] = (bf16)(o[n][r] * inv);
  }
}

// ---------------------------------------------------------------------------
// Launch
// ---------------------------------------------------------------------------
extern "C" void kernel_launch(void* const* d_in, const int* in_sizes, int n_in,
                              void* d_out, int out_size, void* d_ws, size_t ws_size,
                              hipStream_t stream) {
  const float* x = (const float*)d_in[0];       // [8192, 1024] fp32
  const float* w_qkv = (const float*)d_in[1];   // [1024, 3072] fp32
  const float* w_proj = (const float*)d_in[2];  // [1024, 1024] fp32
  float* out = (float*)d_out;                   // [8192, 1024] fp32

  bf16* ws = (bf16*)d_ws;
  bf16* x_bf = ws;                                   // [8192,1024]
  bf16* wqkvT = x_bf + (size_t)8192 * 1024;          // [3072,1024]
  bf16* wprojT = wqkvT + 3072 * 1024;                // [1024,1024]
  bf16* qkv = wprojT + 1024 * 1024;                  // [8192,3072]
  bf16* attn_out = qkv + (size_t)8192 * 3072;        // [8192,1024]

  cast_f32_bf16<<<4096, 256, 0, stream>>>(x, x_bf);
  transpose_f32_bf16<<<dim3(48, 16), 256, 0, stream>>>(w_qkv, wqkvT, 1024, 3072);
  transpose_f32_bf16<<<dim3(16, 16), 256, 0, stream>>>(w_proj, wprojT, 1024, 1024);
  gemm_lds<bf16><<<dim3(24, 64), 256, 0, stream>>>(x_bf, wqkvT, qkv, 8192, 3072, 1024);
  attn_kernel<<<dim3(64, 32), 256, 0, stream>>>(qkv, attn_out);
  gemm_lds<float><<<dim3(8, 64), 256, 0, stream>>>(attn_out, wprojT, out, 8192, 1024, 1024);
}

// Round 4
// 276.406 us; speedup vs baseline: 1.3152x; 1.0196x over previous
//
#include <hip/hip_runtime.h>

typedef __bf16 bf16;
typedef __bf16 bf16x8 __attribute__((ext_vector_type(8)));
typedef float f32x4 __attribute__((ext_vector_type(4)));
typedef unsigned int uint;
typedef unsigned short ushort;

typedef const __attribute__((address_space(1))) void* gas_ptr;
typedef __attribute__((address_space(3))) void* las_ptr;

__device__ __forceinline__ void load16_lds(const void* g, void* l) {
  __builtin_amdgcn_global_load_lds((gas_ptr)g, (las_ptr)l, 16, 0, 0);
}

// ---------------------------------------------------------------------------
// x fp32 -> bf16 cast (8 elems/thread)
// ---------------------------------------------------------------------------
__global__ __launch_bounds__(256) void cast_f32_bf16(
    const float* __restrict__ in, bf16* __restrict__ out) {
  size_t i = (size_t)blockIdx.x * 256 + threadIdx.x;
  const float4* p = reinterpret_cast<const float4*>(in) + i * 2;
  float4 a = p[0], b = p[1];
  bf16x8 v;
  v[0] = (bf16)a.x; v[1] = (bf16)a.y; v[2] = (bf16)a.z; v[3] = (bf16)a.w;
  v[4] = (bf16)b.x; v[5] = (bf16)b.y; v[6] = (bf16)b.z; v[7] = (bf16)b.w;
  reinterpret_cast<bf16x8*>(out)[i] = v;
}

// ---------------------------------------------------------------------------
// Weight transpose + cast: in [K][N] fp32 -> out [N][K] bf16, 64x64 tiles
// ---------------------------------------------------------------------------
__global__ __launch_bounds__(256) void transpose_f32_bf16(
    const float* __restrict__ in, bf16* __restrict__ out, int K, int N) {
  __shared__ __attribute__((aligned(16))) bf16 tile[64 * 72];
  const int k0 = blockIdx.y * 64, n0 = blockIdx.x * 64;
  const int tid = threadIdx.x;
  for (int c = tid; c < 1024; c += 256) {
    int ki = c >> 4, j4 = c & 15;
    float4 f = *reinterpret_cast<const float4*>(in + (size_t)(k0 + ki) * N + n0 + j4 * 4);
    bf16* t = &tile[ki * 72 + j4 * 4];
    t[0] = (bf16)f.x; t[1] = (bf16)f.y; t[2] = (bf16)f.z; t[3] = (bf16)f.w;
  }
  __syncthreads();
  for (int c = tid; c < 512; c += 256) {
    int ni = c >> 3, k8 = c & 7;
    bf16x8 v;
    for (int j = 0; j < 8; j++) v[j] = tile[(k8 * 8 + j) * 72 + ni];
    *reinterpret_cast<bf16x8*>(out + (size_t)(n0 + ni) * K + k0 + k8 * 8) = v;
  }
}

// ---------------------------------------------------------------------------
// GEMM: C[M,N] = A[M,K] * Bt[N,K]^T  (bf16 in, f32 accum, CT out)
// 128x128 tile, BK=64. Staging via global_load_lds width=16.
// XCD-aware bijective block swizzle (T1): nwg % 8 == 0 guaranteed by launcher.
// LDS chunk layout: 16B chunk p holds logical (row=p>>3, kc=(p&7)^(row&7)).
// ---------------------------------------------------------------------------
template <typename CT>
__global__ __launch_bounds__(256, 2) void gemm_lds(
    const bf16* __restrict__ A, const bf16* __restrict__ Bt,
    CT* __restrict__ C, int M, int N, int K) {
  __shared__ __attribute__((aligned(16))) bf16 As[128 * 64];
  __shared__ __attribute__((aligned(16))) bf16 Bs[128 * 64];
  const int tid = threadIdx.x;
  const int wave = tid >> 6;
  const int lane = tid & 63;
  const int l15 = lane & 15;
  const int quad = lane >> 4;
  // XCD swizzle: XCD j owns a contiguous chunk of tile space (L2 panel reuse)
  const int nwg = gridDim.x * gridDim.y;
  const int orig = blockIdx.y * gridDim.x + blockIdx.x;
  const int swz = (orig & 7) * (nwg >> 3) + (orig >> 3);
  const int m0 = (swz / gridDim.x) * 128;
  const int n0 = (swz % gridDim.x) * 128;
  const int wm = (wave >> 1) * 64;
  const int wn = (wave & 1) * 64;

  f32x4 acc[4][4] = {};

  for (int kt = 0; kt < K; kt += 64) {
    __syncthreads();
    for (int it = 0; it < 4; ++it) {
      int p = it * 256 + wave * 64 + lane;
      int row = p >> 3, kc = (p & 7) ^ (row & 7);
      load16_lds(A + (size_t)(m0 + row) * K + kt + kc * 8, &As[p * 8]);
      load16_lds(Bt + (size_t)(n0 + row) * K + kt + kc * 8, &Bs[p * 8]);
    }
    __syncthreads();
    for (int kk = 0; kk < 64; kk += 32) {
      const int kc = (kk >> 3) + quad;
      bf16x8 af[4], bfr[4];
      for (int i = 0; i < 4; i++) {
        int row = wm + i * 16 + l15;
        af[i] = *reinterpret_cast<const bf16x8*>(&As[(row * 8 + (kc ^ (row & 7))) * 8]);
      }
      for (int j = 0; j < 4; j++) {
        int row = wn + j * 16 + l15;
        bfr[j] = *reinterpret_cast<const bf16x8*>(&Bs[(row * 8 + (kc ^ (row & 7))) * 8]);
      }
      for (int i = 0; i < 4; i++)
        for (int j = 0; j < 4; j++)
          acc[i][j] = __builtin_amdgcn_mfma_f32_16x16x32_bf16(af[i], bfr[j], acc[i][j], 0, 0, 0);
    }
  }

  for (int i = 0; i < 4; i++)
    for (int j = 0; j < 4; j++)
      for (int r = 0; r < 4; r++) {
        int row = m0 + wm + i * 16 + quad * 4 + r;
        int col = n0 + wn + j * 16 + l15;
        C[(size_t)row * N + col] = (CT)acc[i][j][r];
      }
}

// ---------------------------------------------------------------------------
// Flash attention, swapped-QK^T form. qkv: [B*T, 3072] bf16.
// Grid (B*H=64, T/128=16); 8 waves x 16 q-rows (QBLK=128).
// K/V LDS double-buffered -> ONE barrier per KV tile.
// Staging role-split: waves 0-3 stage V, waves 4-7 stage K (prefetch regs).
// S^T = mfma(A=K_frag, B=Q_frag); rho-permuted K rows put S^T C-regs exactly
// in PV A-fragment order (no P round-trip). In-register online softmax with
// max3 chain + defer-max (thr 8, log2 domain). Row-sum via ones-column MFMA.
// ---------------------------------------------------------------------------
__device__ __forceinline__ int vs_dw(int d, int kdw) {
  return d * 32 + (kdw ^ ((((d >> 3) ^ d) & 7) * 4));
}

__global__ __launch_bounds__(512, 4) void attn_kernel(
    const bf16* __restrict__ qkv, bf16* __restrict__ out) {
  __shared__ __attribute__((aligned(16))) bf16 Ks[2][64 * 64];  // XOR-chunk, rho-rows
  __shared__ __attribute__((aligned(16))) uint Vs[2][64 * 32];  // swizzled [d][keypair]

  const int tid = threadIdx.x;
  const int wave = tid >> 6;    // 0..7
  const int lane = tid & 63;
  const int l15 = lane & 15;
  const int quad = lane >> 4;
  const int b = blockIdx.x >> 4;
  const int h = blockIdx.x & 15;
  const int qt0 = blockIdx.y * 128;
  const bf16* base = qkv + (size_t)b * 2048 * 3072 + h * 64;
  const float L2E = 1.44269504f;

  // Q fragments (B-operand), pre-scaled by log2(e)
  bf16x8 aq0, aq1;
  {
    const bf16* qrow = base + (size_t)(qt0 + wave * 16 + l15) * 3072;
    aq0 = *reinterpret_cast<const bf16x8*>(qrow + quad * 8);
    aq1 = *reinterpret_cast<const bf16x8*>(qrow + 32 + quad * 8);
    for (int j = 0; j < 8; j++) {
      aq0[j] = (bf16)((float)aq0[j] * L2E);
      aq1[j] = (bf16)((float)aq1[j] * L2E);
    }
  }

  // ones-column B fragment: B[k][0] = 1 -> lanes with l15==0 hold 1s
  bf16x8 bones = {};
  if (l15 == 0)
    for (int j = 0; j < 8; j++) bones[j] = (bf16)1.0f;

  float m_q = -1e30f;     // running max for query l15 (replicated across quads)
  f32x4 o[4] = {};
  f32x4 l_acc = {};

  // staging role: waves 0-3 stage V, waves 4-7 stage K
  const int t2 = tid & 255;
  const int kp = t2 >> 3;    // V: key pair 0..31 / K: key row 0..31 (and +32)
  const int oct = t2 & 7;    // d octet / d chunk
  const bool vrole = (wave < 4);
  // K staging dest (rho-permuted rows, XOR chunks) — same formulas as verified
  const int prow = ((kp & 4) << 2) | ((kp & 24) >> 1) | (kp & 3);
  const int kxor = oct ^ (prow & 7);
  const int kdst0 = (prow * 8 + kxor) * 8;
  const int kdst1 = kdst0 + 32 * 64;

  // ---- prologue: prefetch KV tile 0 into registers (role-split) ----
  bf16x8 pre0, pre1;
  if (vrole) {
    const bf16* v0p = base + (size_t)(2 * kp) * 3072 + 2048 + oct * 8;
    pre0 = *reinterpret_cast<const bf16x8*>(v0p);
    pre1 = *reinterpret_cast<const bf16x8*>(v0p + 3072);
  } else {
    const bf16* kb = base + 1024 + (size_t)kp * 3072 + oct * 8;
    pre0 = *reinterpret_cast<const bf16x8*>(kb);
    pre1 = *reinterpret_cast<const bf16x8*>(kb + (size_t)32 * 3072);
  }

  for (int kt = 0; kt < 2048; kt += 64) {
    const int cur = (kt >> 6) & 1;
    // ---- write prefetched tile t into buf[cur] ----
    if (vrole) {
      const ushort* u0 = reinterpret_cast<const ushort*>(&pre0);
      const ushort* u1 = reinterpret_cast<const ushort*>(&pre1);
      for (int i = 0; i < 8; i++)
        Vs[cur][vs_dw(oct * 8 + i, kp)] = (uint)u0[i] | ((uint)u1[i] << 16);
    } else {
      *reinterpret_cast<bf16x8*>(&Ks[cur][kdst0]) = pre0;
      *reinterpret_cast<bf16x8*>(&Ks[cur][kdst1]) = pre1;
    }
    __syncthreads();   // single barrier per tile (double-buffered)

    // ---- issue next-tile global loads; latency hides under compute ----
    if (kt + 64 < 2048) {
      const bf16* nb = base + (size_t)(kt + 64) * 3072;
      if (vrole) {
        const bf16* v0p = nb + (size_t)(2 * kp) * 3072 + 2048 + oct * 8;
        pre0 = *reinterpret_cast<const bf16x8*>(v0p);
        pre1 = *reinterpret_cast<const bf16x8*>(v0p + 3072);
      } else {
        const bf16* kb = nb + 1024 + (size_t)kp * 3072 + oct * 8;
        pre0 = *reinterpret_cast<const bf16x8*>(kb);
        pre1 = *reinterpret_cast<const bf16x8*>(kb + (size_t)32 * 3072);
      }
    }

    // ---- S^T = K (Q*log2e)^T : mfma(A=K_frag, B=Q_frag) ----
    f32x4 s[4];
    __builtin_amdgcn_s_setprio(1);
    for (int n = 0; n < 4; n++) {
      int row = n * 16 + l15;
      int xr = row & 7;
      bf16x8 ak0 = *reinterpret_cast<const bf16x8*>(&Ks[cur][(row * 8 + (quad ^ xr)) * 8]);
      bf16x8 ak1 = *reinterpret_cast<const bf16x8*>(&Ks[cur][(row * 8 + ((4 + quad) ^ xr)) * 8]);
      f32x4 z = {};
      z = __builtin_amdgcn_mfma_f32_16x16x32_bf16(ak0, aq0, z, 0, 0, 0);
      z = __builtin_amdgcn_mfma_f32_16x16x32_bf16(ak1, aq1, z, 0, 0, 0);
      s[n] = z;
    }
    __builtin_amdgcn_s_setprio(0);

    // ---- per-query online softmax, fully in-register (max3-fusable chain) --
    float mt = fmaxf(fmaxf(s[0][0], s[0][1]), s[0][2]);
    mt = fmaxf(fmaxf(mt, s[0][3]), s[1][0]);
    mt = fmaxf(fmaxf(mt, s[1][1]), s[1][2]);
    mt = fmaxf(fmaxf(mt, s[1][3]), s[2][0]);
    mt = fmaxf(fmaxf(mt, s[2][1]), s[2][2]);
    mt = fmaxf(fmaxf(mt, s[2][3]), s[3][0]);
    mt = fmaxf(fmaxf(mt, s[3][1]), s[3][2]);
    mt = fmaxf(mt, s[3][3]);
    mt = fmaxf(mt, __shfl_xor(mt, 16, 64));
    mt = fmaxf(mt, __shfl_xor(mt, 32, 64));

    // defer-max: only rescale when the tile max grew by > 8 (log2 domain)
    if (!__all(mt - m_q <= 8.0f)) {
      float mn = fmaxf(m_q, mt);
      float alpha = __builtin_amdgcn_exp2f(m_q - mn);
      m_q = mn;
      float a0 = __shfl(alpha, quad * 4 + 0, 64);
      float a1 = __shfl(alpha, quad * 4 + 1, 64);
      float a2 = __shfl(alpha, quad * 4 + 2, 64);
      float a3 = __shfl(alpha, quad * 4 + 3, 64);
      l_acc[0] *= a0; l_acc[1] *= a1; l_acc[2] *= a2; l_acc[3] *= a3;
      for (int n = 0; n < 4; n++) {
        o[n][0] *= a0; o[n][1] *= a1; o[n][2] *= a2; o[n][3] *= a3;
      }
    }

    // P in PV A-fragment order directly (thanks to rho-permuted K rows)
    bf16x8 ap0, ap1;
    for (int r = 0; r < 4; r++) {
      ap0[r]     = (bf16)__builtin_amdgcn_exp2f(s[0][r] - m_q);
      ap0[4 + r] = (bf16)__builtin_amdgcn_exp2f(s[1][r] - m_q);
      ap1[r]     = (bf16)__builtin_amdgcn_exp2f(s[2][r] - m_q);
      ap1[4 + r] = (bf16)__builtin_amdgcn_exp2f(s[3][r] - m_q);
    }

    __builtin_amdgcn_s_setprio(1);
    // row-sum via ones-column (C-layout rows = queries quad*4+r)
    l_acc = __builtin_amdgcn_mfma_f32_16x16x32_bf16(ap0, bones, l_acc, 0, 0, 0);
    l_acc = __builtin_amdgcn_mfma_f32_16x16x32_bf16(ap1, bones, l_acc, 0, 0, 0);

    // O += P V  (V fragments from swizzled Vs)
    for (int n = 0; n < 4; n++) {
      int d = n * 16 + l15;
      uint4 u0 = *reinterpret_cast<const uint4*>(&Vs[cur][vs_dw(d, quad * 4)]);
      uint4 u1 = *reinterpret_cast<const uint4*>(&Vs[cur][vs_dw(d, 16 + quad * 4)]);
      bf16x8 bv0 = *reinterpret_cast<const bf16x8*>(&u0);
      bf16x8 bv1 = *reinterpret_cast<const bf16x8*>(&u1);
      o[n] = __builtin_amdgcn_mfma_f32_16x16x32_bf16(ap0, bv0, o[n], 0, 0, 0);
      o[n] = __builtin_amdgcn_mfma_f32_16x16x32_bf16(ap1, bv1, o[n], 0, 0, 0);
    }
    __builtin_amdgcn_s_setprio(0);
  }

  for (int r = 0; r < 4; r++) {
    float lv = __shfl(l_acc[r], quad * 16, 64);
    float inv = 1.0f / lv;
    int q = qt0 + wave * 16 + quad * 4 + r;
    bf16* orow = out + (size_t)(b * 2048 + q) * 1024 + h * 64;
    for (int n = 0; n < 4; n++) orow[n * 16 + l15] = (bf16)(o[n][r] * inv);
  }
}

// ---------------------------------------------------------------------------
// Launch
// ---------------------------------------------------------------------------
extern "C" void kernel_launch(void* const* d_in, const int* in_sizes, int n_in,
                              void* d_out, int out_size, void* d_ws, size_t ws_size,
                              hipStream_t stream) {
  const float* x = (const float*)d_in[0];       // [8192, 1024] fp32
  const float* w_qkv = (const float*)d_in[1];   // [1024, 3072] fp32
  const float* w_proj = (const float*)d_in[2];  // [1024, 1024] fp32
  float* out = (float*)d_out;                   // [8192, 1024] fp32

  bf16* ws = (bf16*)d_ws;
  bf16* x_bf = ws;                                   // [8192,1024]
  bf16* wqkvT = x_bf + (size_t)8192 * 1024;          // [3072,1024]
  bf16* wprojT = wqkvT + 3072 * 1024;                // [1024,1024]
  bf16* qkv = wprojT + 1024 * 1024;                  // [8192,3072]
  bf16* attn_out = qkv + (size_t)8192 * 3072;        // [8192,1024]

  cast_f32_bf16<<<4096, 256, 0, stream>>>(x, x_bf);
  transpose_f32_bf16<<<dim3(48, 16), 256, 0, stream>>>(w_qkv, wqkvT, 1024, 3072);
  transpose_f32_bf16<<<dim3(16, 16), 256, 0, stream>>>(w_proj, wprojT, 1024, 1024);
  gemm_lds<bf16><<<dim3(24, 64), 256, 0, stream>>>(x_bf, wqkvT, qkv, 8192, 3072, 1024);
  attn_kernel<<<dim3(64, 16), 512, 0, stream>>>(qkv, attn_out);
  gemm_lds<float><<<dim3(8, 64), 256, 0, stream>>>(attn_out, wprojT, out, 8192, 1024, 1024);
}